// Round 12
// baseline (188.077 us; speedup 1.0000x reference)
//
#include <hip/hip_runtime.h>
#include <hip/hip_bf16.h>
#include <stdint.h>

// VectorQuantizer on MI355X.
//   z: (8,256,32,32) f32  -> rows = 8192, K = 256
//   embed_w: (16384,256) f32
// out: z_q (2097152 f32) + loss (1 f32)
// k_prep: z->bf16 blocked; ew->bf16 blocked (LDS-tiled, coalesced) + -0.5||e||^2
// k_main: fused GEMM+argmax, ring-3 LDS (52KB -> 3 blocks/CU), counted vmcnt(4)
// k_fin : reduce 16 partials -> full-row 1KB gathers -> LDS transpose -> out+loss

typedef __attribute__((ext_vector_type(8))) short bf16x8;
typedef __attribute__((ext_vector_type(8))) unsigned short ushort8v;
typedef __attribute__((ext_vector_type(4))) float f32x4;

__device__ __forceinline__ unsigned short f2bf(float f) {
  unsigned u = __float_as_uint(f);
  return (unsigned short)((u + 0x7FFFu + ((u >> 16) & 1u)) >> 16);
}

typedef const __attribute__((address_space(1))) unsigned char* gas1;
typedef __attribute__((address_space(3))) unsigned char* las3;
__device__ __forceinline__ void cp16g(const void* g, void* l) {
  __builtin_amdgcn_global_load_lds((gas1)g, (las3)l, 16, 0, 0);
}

// ---------------- P: fused prep ------------------------------------------------
__global__ void k_prep(const float* __restrict__ z, const float* __restrict__ ew,
                       unsigned short* __restrict__ zp, unsigned short* __restrict__ ep,
                       float* __restrict__ h2, float* __restrict__ out) {
  __shared__ unsigned char smem[16896];
  int bid = blockIdx.x;
  int t = threadIdx.x;
  if (bid < 512) {
    float (*tile)[132] = (float (*)[132])smem;
    int b = bid >> 6, ct = (bid >> 3) & 7, hwt = bid & 7;
    const float* src = z + b * 262144 + ct * 32768 + hwt * 128;
#pragma unroll
    for (int it = 0; it < 4; ++it) {
      int cell = it * 1024 + t * 4;
      int cl = cell >> 7, hl = cell & 127;
      float4 v = *(const float4*)(src + cl * 1024 + hl);
      *(float4*)(&tile[cl][hl]) = v;
    }
    __syncthreads();
    int mt = b * 8 + hwt;
    unsigned short* dst = zp + mt * 32768 + ct * 4096;  // ct == kstep
#pragma unroll
    for (int it = 0; it < 2; ++it) {
      int cell = it * 256 + t;
      int kg = cell >> 7, r = cell & 127;
      ushort8v v;
#pragma unroll
      for (int j = 0; j < 8; ++j) v[j] = f2bf(tile[kg * 8 + j][r]);
      *(ushort8v*)(dst + cell * 8) = v;
    }
  } else {
    unsigned short (*et)[264] = (unsigned short (*)[264])smem;  // 16B-aligned rows
    if (bid == 512 && t == 0) out[2097152] = 0.0f;
    int n0 = (bid - 512) * 32;
    int lane = t & 63;
    // read phase: coalesced 1KB code rows -> bf16 LDS tile + h2 reduce
#pragma unroll
    for (int it = 0; it < 4; ++it) {
      int c = it * 8 + (t >> 5);
      int k0 = (t & 31) * 8;
      const float4 x = *(const float4*)(ew + (n0 + c) * 256 + k0);
      const float4 y = *(const float4*)(ew + (n0 + c) * 256 + k0 + 4);
      float s = x.x * x.x + x.y * x.y + x.z * x.z + x.w * x.w
              + y.x * y.x + y.y * y.y + y.z * y.z + y.w * y.w;
      ushort8v v;
      v[0] = f2bf(x.x); v[1] = f2bf(x.y); v[2] = f2bf(x.z); v[3] = f2bf(x.w);
      v[4] = f2bf(y.x); v[5] = f2bf(y.y); v[6] = f2bf(y.z); v[7] = f2bf(y.w);
      *(ushort8v*)(&et[c][k0]) = v;
#pragma unroll
      for (int off = 1; off <= 16; off <<= 1) s += __shfl_xor(s, off);
      if ((lane & 31) == 0) h2[n0 + c] = -0.5f * s;
    }
    __syncthreads();
    // write phase: blocked layout, 512B-contiguous per (ks,kg) chunk
    int nb = n0 >> 7, col0 = n0 & 127;
#pragma unroll
    for (int it = 0; it < 4; ++it) {
      int cellk = it * 8 + (t >> 5);
      int c = t & 31;
      int ks = cellk >> 2, kg = cellk & 3;
      ushort8v v = *(const ushort8v*)(&et[c][cellk * 8]);
      *(ushort8v*)(ep + nb * 32768 + ks * 4096 + kg * 1024 + (col0 + c) * 8) = v;
    }
  }
}

// ---------------- Main: fused GEMM + argmax ------------------------------------
// grid (16 seg, 64 mt), 256 thr. 32 steps; step s = nb*4+ph: cols [nb*128,+128),
// k [ph*64,+64). Ring-3 B buffers (16 KB, rotating uniform byte offset),
// prefetch depth 2, vmcnt(4) steady. In-loop VMEM is ONLY cp16 staging
// (4/wave/step) -> ledger exact. Bias -0.5||e||^2 applied at the ph==3 fold
// via ds_read (lgkmcnt, doesn't touch the vmcnt ledger).
// 52 KB LDS -> 3 blocks/CU.
__global__ __launch_bounds__(256, 3) void k_main(
    const unsigned short* __restrict__ zp, const unsigned short* __restrict__ ep,
    const float* __restrict__ h2, int2* __restrict__ partial) {
  __shared__ unsigned char ring[49152];
  __shared__ float hbuf[1024];
  int seg = blockIdx.x;   // 0..15
  int mt = blockIdx.y;    // 0..63
  int t = threadIdx.x, wv = t >> 6, lane = t & 63;
  int l15 = lane & 15, kg = lane >> 4;

  // A tile -> registers: av[m*8+ks], 16B fragments
  bf16x8 av[16];
  const unsigned short* abase = zp + mt * 32768;
#pragma unroll
  for (int m = 0; m < 2; ++m)
#pragma unroll
    for (int ks = 0; ks < 8; ++ks)
      av[m * 8 + ks] = *(const bf16x8*)(abase + ks * 4096 + kg * 1024 +
                                        (wv * 32 + m * 16 + l15) * 8);

  const unsigned char* bsrc = (const unsigned char*)ep + seg * 524288;
  const unsigned char* bstage = bsrc + wv * 1024 + lane * 16;  // per-lane src
  int ldsw = wv * 1024;                                        // wave-uniform dest

  // prologue (9 vmem/wave): h2 (1) + stage0 -> buf0 (4) + stage1 -> buf1 (4)
  cp16g((const unsigned char*)(h2 + seg * 1024) + ldsw + lane * 16,
        (unsigned char*)hbuf + ldsw);
#pragma unroll
  for (int i = 0; i < 4; ++i)
    cp16g(bstage + i * 4096, &ring[i * 4096 + ldsw]);
  __builtin_amdgcn_sched_barrier(0);   // pin: {h, stage0} strictly before stage1
#pragma unroll
  for (int i = 0; i < 4; ++i)
    cp16g(bstage + 16384 + i * 4096, &ring[16384 + i * 4096 + ldsw]);

  f32x4 acc[2][8];
  float best[2][4];
#pragma unroll
  for (int m = 0; m < 2; ++m)
#pragma unroll
    for (int r = 0; r < 4; ++r) best[m][r] = -3.4e38f;

  unsigned rd = 0u, wr = 32768u;  // rotating ring byte offsets (wave-uniform)

#define KSTEP(PH, NB, DOSTAGE, VM)                                              \
  {                                                                             \
    asm volatile("s_waitcnt vmcnt(" VM ")" ::: "memory");                       \
    __builtin_amdgcn_s_barrier();                                               \
    if (DOSTAGE) {                                                              \
      const unsigned char* sg = bstage + ((NB) * 4 + (PH) + 2) * 16384;         \
      _Pragma("unroll") for (int i = 0; i < 4; ++i)                             \
        cp16g(sg + i * 4096, &ring[wr + i * 4096 + ldsw]);                      \
    }                                                                           \
    if ((PH) == 0) {                                                            \
      _Pragma("unroll") for (int nf = 0; nf < 8; ++nf)                          \
        acc[0][nf] = acc[1][nf] = (f32x4){0.f, 0.f, 0.f, 0.f};                  \
    }                                                                           \
    __builtin_amdgcn_s_setprio(1);                                              \
    _Pragma("unroll") for (int k2 = 0; k2 < 2; ++k2) {                          \
      bf16x8 bv[8];                                                             \
      _Pragma("unroll") for (int nf = 0; nf < 8; ++nf)                          \
        bv[nf] = *(const bf16x8*)(&ring[rd + k2 * 8192 + kg * 2048 +            \
                                        (nf * 16 + l15) * 16]);                 \
      _Pragma("unroll") for (int m = 0; m < 2; ++m)                             \
        _Pragma("unroll") for (int nf = 0; nf < 8; ++nf)                        \
          acc[m][nf] = __builtin_amdgcn_mfma_f32_16x16x32_bf16(                 \
              av[m * 8 + (PH) * 2 + k2], bv[nf], acc[m][nf], 0, 0, 0);          \
    }                                                                           \
    __builtin_amdgcn_s_setprio(0);                                              \
    if ((PH) == 3) {                                                            \
      unsigned colbase = (unsigned)((NB) * 128 + l15);                          \
      _Pragma("unroll") for (int nf = 0; nf < 8; ++nf) {                        \
        float h = hbuf[(NB) * 128 + nf * 16 + l15];                             \
        unsigned lcol = colbase + nf * 16u;                                     \
        _Pragma("unroll") for (int m = 0; m < 2; ++m)                           \
          _Pragma("unroll") for (int r = 0; r < 4; ++r) {                       \
            unsigned p = (__float_as_uint(acc[m][nf][r] + h) & 0xFFFFF800u) | lcol; \
            best[m][r] = fmaxf(best[m][r], __uint_as_float(p));                 \
          }                                                                     \
      }                                                                         \
    }                                                                           \
    rd = (rd == 32768u) ? 0u : rd + 16384u;                                     \
    wr = (wr == 32768u) ? 0u : wr + 16384u;                                     \
  }

#pragma unroll 1
  for (int nb = 0; nb < 7; ++nb) {
    KSTEP(0, nb, 1, "4")
    KSTEP(1, nb, 1, "4")
    KSTEP(2, nb, 1, "4")
    KSTEP(3, nb, 1, "4")
  }
  KSTEP(0, 7, 1, "4")   // stages step 30
  KSTEP(1, 7, 1, "4")   // stages step 31 (last)
  KSTEP(2, 7, 0, "4")
  KSTEP(3, 7, 0, "0")
#undef KSTEP

  // cross-lane (16 cols/group) argmax reduce, write per-(row,segment) partial
#pragma unroll
  for (int m = 0; m < 2; ++m)
#pragma unroll
    for (int r = 0; r < 4; ++r) {
      float bvv = best[m][r];
#pragma unroll
      for (int off = 1; off <= 8; off <<= 1) bvv = fmaxf(bvv, __shfl_xor(bvv, off));
      if (l15 == 0) {
        unsigned bits = __float_as_uint(bvv);
        int gidx = seg * 1024 + (int)(bits & 0x7FFu);
        int row = mt * 128 + wv * 32 + m * 16 + kg * 4 + r;
        partial[seg * 8192 + row] = make_int2((int)bits, gidx);
      }
    }
}

// -------- Final: reduce partials -> full-row gather -> transpose -> out+loss ---
// 256 blocks = (b 0..7, pxt 0..31); 32 pixels x 256 ch each.
// Gather: one wave reads one 1KB code row fully coalesced (64 lanes x 16B).
__global__ void k_fin(const int2* __restrict__ partial, const float* __restrict__ ew,
                      const float* __restrict__ z, float* __restrict__ out) {
  __shared__ float tile[32][260];   // [px][ch], padded
  __shared__ int codeIdx[32];
  int bid = blockIdx.x;
  int b = bid >> 5, pxt = bid & 31;
  int t = threadIdx.x, wv = t >> 6, lane = t & 63;
  if (t < 32) {
    int row = b * 1024 + pxt * 32 + t;
    float bb = -3.4e38f;
    int bi = 0;
#pragma unroll
    for (int s = 0; s < 16; ++s) {
      int2 p = partial[s * 8192 + row];
      float v = __int_as_float(p.x);
      if (v > bb) { bb = v; bi = p.y; }
    }
    codeIdx[t] = bi;
  }
  __syncthreads();
#pragma unroll
  for (int i = 0; i < 8; ++i) {
    int px = wv * 8 + i;
    int idx = codeIdx[px];
    float4 v = *(const float4*)(ew + idx * 256 + lane * 4);
    *(float4*)(&tile[px][lane * 4]) = v;
  }
  __syncthreads();
  float ls = 0.0f;
  int zbase = b * 262144 + pxt * 32;
#pragma unroll
  for (int j = 0; j < 8; ++j) {
    int c = wv * 64 + j * 8 + (lane >> 3);
    int p4 = (lane & 7) * 4;
    float4 q;
    q.x = tile[p4][c]; q.y = tile[p4 + 1][c]; q.z = tile[p4 + 2][c]; q.w = tile[p4 + 3][c];
    const float* zp_ = z + zbase + c * 1024 + p4;
    float4 zv = *(const float4*)zp_;
    float dx = q.x - zv.x, dy = q.y - zv.y, dz = q.z - zv.z, dw = q.w - zv.w;
    ls += dx * dx + dy * dy + dz * dz + dw * dw;
    *(float4*)(out + zbase + c * 1024 + p4) = q;
  }
#pragma unroll
  for (int off = 32; off; off >>= 1) ls += __shfl_xor(ls, off);
  if (lane == 0) atomicAdd(out + 2097152, ls * (2.0f / 2097152.0f));
}

extern "C" void kernel_launch(void* const* d_in, const int* in_sizes, int n_in,
                              void* d_out, int out_size, void* d_ws, size_t ws_size,
                              hipStream_t stream) {
  const float* z = (const float*)d_in[0];
  const float* ew = (const float*)d_in[1];
  float* out = (float*)d_out;
  unsigned char* ws = (unsigned char*)d_ws;
  unsigned short* zp = (unsigned short*)ws;                           // 4 MB
  unsigned short* ep = (unsigned short*)(ws + (4u << 20));            // 8 MB
  float* h2 = (float*)(ws + (12u << 20));                             // 64 KB
  int2* partial = (int2*)(ws + (12u << 20) + 65536);                  // 1 MB

  k_prep<<<1024, 256, 0, stream>>>(z, ew, zp, ep, h2, out);
  k_main<<<dim3(16, 64), 256, 0, stream>>>(zp, ep, h2, partial);
  k_fin<<<256, 256, 0, stream>>>(partial, ew, z, out);
}

// Round 13
// 155.561 us; speedup vs baseline: 1.2090x; 1.2090x over previous
//
#include <hip/hip_runtime.h>
#include <hip/hip_bf16.h>
#include <stdint.h>

// VectorQuantizer on MI355X.
//   z: (8,256,32,32) f32  -> rows = 8192, K = 256
//   embed_w: (16384,256) f32
// out: z_q (2097152 f32) + loss (1 f32)
// k_prep: z->bf16 blocked; ew->bf16 blocked (LDS-tiled, coalesced) + -0.5||e||^2
// k_main: R11-measured version: ring-4 LDS, counted vmcnt(4), launch_bounds(256,2)
// k_fin : parallel 16-seg reduce -> full-row 1KB gathers -> conflict-free transpose

typedef __attribute__((ext_vector_type(8))) short bf16x8;
typedef __attribute__((ext_vector_type(8))) unsigned short ushort8v;
typedef __attribute__((ext_vector_type(4))) float f32x4;

__device__ __forceinline__ unsigned short f2bf(float f) {
  unsigned u = __float_as_uint(f);
  return (unsigned short)((u + 0x7FFFu + ((u >> 16) & 1u)) >> 16);
}

typedef const __attribute__((address_space(1))) unsigned char* gas1;
typedef __attribute__((address_space(3))) unsigned char* las3;
__device__ __forceinline__ void cp16g(const void* g, void* l) {
  __builtin_amdgcn_global_load_lds((gas1)g, (las3)l, 16, 0, 0);
}

// ---------------- P: fused prep ------------------------------------------------
__global__ void k_prep(const float* __restrict__ z, const float* __restrict__ ew,
                       unsigned short* __restrict__ zp, unsigned short* __restrict__ ep,
                       float* __restrict__ h2, float* __restrict__ out) {
  __shared__ unsigned char smem[16896];
  int bid = blockIdx.x;
  int t = threadIdx.x;
  if (bid < 512) {
    float (*tile)[132] = (float (*)[132])smem;
    int b = bid >> 6, ct = (bid >> 3) & 7, hwt = bid & 7;
    const float* src = z + b * 262144 + ct * 32768 + hwt * 128;
#pragma unroll
    for (int it = 0; it < 4; ++it) {
      int cell = it * 1024 + t * 4;
      int cl = cell >> 7, hl = cell & 127;
      float4 v = *(const float4*)(src + cl * 1024 + hl);
      *(float4*)(&tile[cl][hl]) = v;
    }
    __syncthreads();
    int mt = b * 8 + hwt;
    unsigned short* dst = zp + mt * 32768 + ct * 4096;  // ct == kstep
#pragma unroll
    for (int it = 0; it < 2; ++it) {
      int cell = it * 256 + t;
      int kg = cell >> 7, r = cell & 127;
      ushort8v v;
#pragma unroll
      for (int j = 0; j < 8; ++j) v[j] = f2bf(tile[kg * 8 + j][r]);
      *(ushort8v*)(dst + cell * 8) = v;
    }
  } else {
    unsigned short (*et)[264] = (unsigned short (*)[264])smem;  // 16B-aligned rows
    if (bid == 512 && t == 0) out[2097152] = 0.0f;
    int n0 = (bid - 512) * 32;
    int lane = t & 63;
    // read phase: coalesced 1KB code rows -> bf16 LDS tile + h2 reduce
#pragma unroll
    for (int it = 0; it < 4; ++it) {
      int c = it * 8 + (t >> 5);
      int k0 = (t & 31) * 8;
      const float4 x = *(const float4*)(ew + (n0 + c) * 256 + k0);
      const float4 y = *(const float4*)(ew + (n0 + c) * 256 + k0 + 4);
      float s = x.x * x.x + x.y * x.y + x.z * x.z + x.w * x.w
              + y.x * y.x + y.y * y.y + y.z * y.z + y.w * y.w;
      ushort8v v;
      v[0] = f2bf(x.x); v[1] = f2bf(x.y); v[2] = f2bf(x.z); v[3] = f2bf(x.w);
      v[4] = f2bf(y.x); v[5] = f2bf(y.y); v[6] = f2bf(y.z); v[7] = f2bf(y.w);
      *(ushort8v*)(&et[c][k0]) = v;
#pragma unroll
      for (int off = 1; off <= 16; off <<= 1) s += __shfl_xor(s, off);
      if ((lane & 31) == 0) h2[n0 + c] = -0.5f * s;
    }
    __syncthreads();
    // write phase: blocked layout, 512B-contiguous per (ks,kg) chunk
    int nb = n0 >> 7, col0 = n0 & 127;
#pragma unroll
    for (int it = 0; it < 4; ++it) {
      int cellk = it * 8 + (t >> 5);
      int c = t & 31;
      int ks = cellk >> 2, kg = cellk & 3;
      ushort8v v = *(const ushort8v*)(&et[c][cellk * 8]);
      *(ushort8v*)(ep + nb * 32768 + ks * 4096 + kg * 1024 + (col0 + c) * 8) = v;
    }
  }
}

// ---------------- Main: fused GEMM + argmax (R11-measured version) -------------
// grid (16 seg, 64 mt), 256 thr. 32 steps; step s = nb*4+ph: cols [nb*128,+128),
// k [ph*64,+64). Ring-4 B buffers (16 KB), prefetch depth 2, vmcnt(4) steady.
__global__ __launch_bounds__(256, 2) void k_main(
    const unsigned short* __restrict__ zp, const unsigned short* __restrict__ ep,
    const float* __restrict__ h2, int2* __restrict__ partial) {
  __shared__ unsigned char ring[4][16384];
  __shared__ float hbuf[1024];
  int seg = blockIdx.x;   // 0..15
  int mt = blockIdx.y;    // 0..63
  int t = threadIdx.x, wv = t >> 6, lane = t & 63;
  int l15 = lane & 15, kg = lane >> 4;

  // A tile -> registers: av[m*8+ks], 16B fragments
  bf16x8 av[16];
  const unsigned short* abase = zp + mt * 32768;
#pragma unroll
  for (int m = 0; m < 2; ++m)
#pragma unroll
    for (int ks = 0; ks < 8; ++ks)
      av[m * 8 + ks] = *(const bf16x8*)(abase + ks * 4096 + kg * 1024 +
                                        (wv * 32 + m * 16 + l15) * 8);

  const unsigned char* bsrc = (const unsigned char*)ep + seg * 524288;
  const unsigned char* bstage = bsrc + wv * 1024 + lane * 16;  // per-lane src
  int ldsw = wv * 1024;                                        // wave-uniform dest

  // prologue: h2 (1 cp16/lane) + stage(0) (4) ... then stage(1) (4)
  cp16g((const unsigned char*)(h2 + seg * 1024) + ldsw + lane * 16,
        (unsigned char*)hbuf + ldsw);
#pragma unroll
  for (int i = 0; i < 4; ++i)
    cp16g(bstage + i * 4096, &ring[0][i * 4096 + ldsw]);
  __builtin_amdgcn_sched_barrier(0);   // pin: {h, stage0} strictly before stage1
#pragma unroll
  for (int i = 0; i < 4; ++i)
    cp16g(bstage + 16384 + i * 4096, &ring[1][i * 4096 + ldsw]);

  f32x4 acc[2][8];
  float best[2][4];
#pragma unroll
  for (int m = 0; m < 2; ++m)
#pragma unroll
    for (int r = 0; r < 4; ++r) best[m][r] = -3.4e38f;

#define KSTEP(PH, NB, DOSTAGE, VM)                                              \
  {                                                                             \
    asm volatile("s_waitcnt vmcnt(" VM ")" ::: "memory");                       \
    __builtin_amdgcn_s_barrier();                                               \
    if (DOSTAGE) {                                                              \
      const unsigned char* sg = bstage + ((NB) * 4 + (PH) + 2) * 16384;         \
      _Pragma("unroll") for (int i = 0; i < 4; ++i)                             \
        cp16g(sg + i * 4096, &ring[((PH) + 2) & 3][i * 4096 + ldsw]);           \
    }                                                                           \
    if ((PH) == 0) {                                                            \
      _Pragma("unroll") for (int nf = 0; nf < 8; ++nf) {                        \
        float h = hbuf[(NB) * 128 + nf * 16 + l15];                             \
        acc[0][nf] = (f32x4){h, h, h, h};                                       \
        acc[1][nf] = acc[0][nf];                                                \
      }                                                                         \
    }                                                                           \
    __builtin_amdgcn_s_setprio(1);                                              \
    _Pragma("unroll") for (int k2 = 0; k2 < 2; ++k2) {                          \
      bf16x8 bv[8];                                                             \
      _Pragma("unroll") for (int nf = 0; nf < 8; ++nf)                          \
        bv[nf] = *(const bf16x8*)(&ring[(PH)][k2 * 8192 + kg * 2048 +           \
                                             (nf * 16 + l15) * 16]);            \
      _Pragma("unroll") for (int m = 0; m < 2; ++m)                             \
        _Pragma("unroll") for (int nf = 0; nf < 8; ++nf)                        \
          acc[m][nf] = __builtin_amdgcn_mfma_f32_16x16x32_bf16(                 \
              av[m * 8 + (PH) * 2 + k2], bv[nf], acc[m][nf], 0, 0, 0);          \
    }                                                                           \
    __builtin_amdgcn_s_setprio(0);                                              \
    if ((PH) == 3) {                                                            \
      unsigned colbase = (unsigned)((NB) * 128 + l15);                          \
      _Pragma("unroll") for (int m = 0; m < 2; ++m)                             \
        _Pragma("unroll") for (int nf = 0; nf < 8; ++nf) {                      \
          unsigned lcol = colbase + nf * 16u;                                   \
          _Pragma("unroll") for (int r = 0; r < 4; ++r) {                       \
            unsigned p = (__float_as_uint(acc[m][nf][r]) & 0xFFFFF800u) | lcol; \
            best[m][r] = fmaxf(best[m][r], __uint_as_float(p));                 \
          }                                                                     \
        }                                                                       \
    }                                                                           \
  }

#pragma unroll 1
  for (int nb = 0; nb < 7; ++nb) {
    KSTEP(0, nb, 1, "4")
    KSTEP(1, nb, 1, "4")
    KSTEP(2, nb, 1, "4")
    KSTEP(3, nb, 1, "4")
  }
  KSTEP(0, 7, 1, "4")   // stages step 30
  KSTEP(1, 7, 1, "4")   // stages step 31 (last)
  KSTEP(2, 7, 0, "4")
  KSTEP(3, 7, 0, "0")
#undef KSTEP

  // cross-lane (16 cols/group) argmax reduce, write per-(row,segment) partial
#pragma unroll
  for (int m = 0; m < 2; ++m)
#pragma unroll
    for (int r = 0; r < 4; ++r) {
      float bvv = best[m][r];
#pragma unroll
      for (int off = 1; off <= 8; off <<= 1) bvv = fmaxf(bvv, __shfl_xor(bvv, off));
      if (l15 == 0) {
        unsigned bits = __float_as_uint(bvv);
        int gidx = seg * 1024 + (int)(bits & 0x7FFu);
        int row = mt * 128 + wv * 32 + m * 16 + kg * 4 + r;
        partial[seg * 8192 + row] = make_int2((int)bits, gidx);
      }
    }
}

// -------- Final: parallel reduce -> full-row gather -> transpose -> out+loss ---
// 256 blocks = (b 0..7, pxt 0..31); 32 pixels x 256 ch each.
// Reduce: all 256 threads, 16-lane-group shfl over the 16 segment partials.
// Gather: one wave reads one 1KB code row fully coalesced (64 lanes x 16B).
// Transpose read: tile stride 261 -> (lane&7)*1044/4 mod 32 all-distinct, no conflict.
__global__ void k_fin(const int2* __restrict__ partial, const float* __restrict__ ew,
                      const float* __restrict__ z, float* __restrict__ out) {
  __shared__ float tile[32][261];
  __shared__ int codeIdx[32];
  int bid = blockIdx.x;
  int b = bid >> 5, pxt = bid & 31;
  int t = threadIdx.x, wv = t >> 6, lane = t & 63;
#pragma unroll
  for (int half = 0; half < 2; ++half) {
    int local = half * 16 + (t >> 4);          // pixel-in-tile 0..31
    int segi = t & 15;                         // 16 consecutive lanes per group
    int row = b * 1024 + pxt * 32 + local;
    int2 p = partial[segi * 8192 + row];
    float v = __int_as_float(p.x);
    int bi = p.y;
#pragma unroll
    for (int off = 1; off <= 8; off <<= 1) {
      float ov = __shfl_xor(v, off);
      int obi = __shfl_xor(bi, off);
      if (ov > v) { v = ov; bi = obi; }
    }
    if (segi == 0) codeIdx[local] = bi;
  }
  __syncthreads();
#pragma unroll
  for (int i = 0; i < 8; ++i) {
    int px = wv * 8 + i;
    int idx = codeIdx[px];
    float4 v = *(const float4*)(ew + idx * 256 + lane * 4);
    *(float4*)(&tile[px][lane * 4]) = v;
  }
  __syncthreads();
  float ls = 0.0f;
  int zbase = b * 262144 + pxt * 32;
#pragma unroll
  for (int j = 0; j < 8; ++j) {
    int c = wv * 64 + j * 8 + (lane >> 3);
    int p4 = (lane & 7) * 4;
    float4 q;
    q.x = tile[p4][c]; q.y = tile[p4 + 1][c]; q.z = tile[p4 + 2][c]; q.w = tile[p4 + 3][c];
    const float* zp_ = z + zbase + c * 1024 + p4;
    float4 zv = *(const float4*)zp_;
    float dx = q.x - zv.x, dy = q.y - zv.y, dz = q.z - zv.z, dw = q.w - zv.w;
    ls += dx * dx + dy * dy + dz * dz + dw * dw;
    *(float4*)(out + zbase + c * 1024 + p4) = q;
  }
#pragma unroll
  for (int off = 32; off; off >>= 1) ls += __shfl_xor(ls, off);
  if (lane == 0) atomicAdd(out + 2097152, ls * (2.0f / 2097152.0f));
}

extern "C" void kernel_launch(void* const* d_in, const int* in_sizes, int n_in,
                              void* d_out, int out_size, void* d_ws, size_t ws_size,
                              hipStream_t stream) {
  const float* z = (const float*)d_in[0];
  const float* ew = (const float*)d_in[1];
  float* out = (float*)d_out;
  unsigned char* ws = (unsigned char*)d_ws;
  unsigned short* zp = (unsigned short*)ws;                           // 4 MB
  unsigned short* ep = (unsigned short*)(ws + (4u << 20));            // 8 MB
  float* h2 = (float*)(ws + (12u << 20));                             // 64 KB
  int2* partial = (int2*)(ws + (12u << 20) + 65536);                  // 1 MB

  k_prep<<<1024, 256, 0, stream>>>(z, ew, zp, ep, h2, out);
  k_main<<<dim3(16, 64), 256, 0, stream>>>(zp, ep, h2, partial);
  k_fin<<<256, 256, 0, stream>>>(partial, ew, z, out);
}